// Round 3
// baseline (557.074 us; speedup 1.0000x reference)
//
#include <hip/hip_runtime.h>
#include <hip/hip_bf16.h>
#include <stdint.h>

#define IN_F  2048
#define HID_F 8192
#define OUT_F 2048
#define BATCH 4096

typedef __attribute__((ext_vector_type(8))) short bf16x8;
typedef __attribute__((ext_vector_type(4))) float f32x4;
typedef __attribute__((ext_vector_type(8))) unsigned short u16x8;

__device__ __forceinline__ unsigned short f32_to_bf16(float f) {
  union { float f; uint32_t u; } v; v.f = f;
  uint32_t u = v.u;
  uint32_t r = u + 0x7FFF + ((u >> 16) & 1);   // RNE
  return (unsigned short)(r >> 16);
}

__device__ __forceinline__ float bf16_to_f32(unsigned short u) {
  union { uint32_t u; float f; } v; v.u = ((uint32_t)u) << 16; return v.f;
}

__device__ __forceinline__ void stage16(const unsigned short* g, unsigned short* l) {
  __builtin_amdgcn_global_load_lds(
      (const __attribute__((address_space(1))) void*)g,
      (__attribute__((address_space(3))) void*)l, 16, 0, 0);
}

// ---------------- pre-pass kernels ----------------

__global__ void cvt_f32_bf16(const float* __restrict__ in, unsigned short* __restrict__ out, int n4) {
  int i = blockIdx.x * blockDim.x + threadIdx.x;
  int stride = gridDim.x * blockDim.x;
  for (int idx = i; idx < n4; idx += stride) {
    float4 v = ((const float4*)in)[idx];
    ushort4 o;
    o.x = f32_to_bf16(v.x); o.y = f32_to_bf16(v.y);
    o.z = f32_to_bf16(v.z); o.w = f32_to_bf16(v.w);
    ((ushort4*)out)[idx] = o;
  }
}

// Both weight transposes in one dispatch.  f32 [R][C] -> bf16 [C][R].
__global__ void transpose2(const float* __restrict__ W1, unsigned short* __restrict__ W1t,
                           const float* __restrict__ W2, unsigned short* __restrict__ W2t) {
  __shared__ unsigned short t[64][72];
  int b = blockIdx.x;
  const float* in; unsigned short* out; int R, C, bx, by;
  if (b < 4096) { in = W1; out = W1t; R = IN_F;  C = HID_F; bx = b & 127; by = b >> 7; }
  else { b -= 4096; in = W2; out = W2t; R = HID_F; C = OUT_F; bx = b & 31;  by = b >> 5; }
  const int tid = threadIdx.x;
  const int r0 = by * 64, c0 = bx * 64;
  #pragma unroll
  for (int p = 0; p < 4; ++p) {
    int f4  = p * 256 + tid;
    int row = f4 >> 4;
    int c   = (f4 & 15) * 4;
    float4 v = *(const float4*)&in[(size_t)(r0 + row) * C + c0 + c];
    t[c + 0][row] = f32_to_bf16(v.x);
    t[c + 1][row] = f32_to_bf16(v.y);
    t[c + 2][row] = f32_to_bf16(v.z);
    t[c + 3][row] = f32_to_bf16(v.w);
  }
  __syncthreads();
  #pragma unroll
  for (int p = 0; p < 2; ++p) {
    int u  = p * 256 + tid;
    int cc = u >> 3;
    int rr = (u & 7) * 8;
    *(u16x8*)&out[(size_t)(c0 + cc) * R + r0 + rr] = *(const u16x8*)&t[cc][rr];
  }
}

// ---------------- 256x256 8-phase GEMM ----------------
// C = epi(A @ Bt^T [+ bias]).  A [M][kstride] bf16, Bt [N][kstride] bf16.
// 8 waves = 2M x 4N, per-wave 128x64 out, BK=64, 2 LDS buffers x 4 half-tiles.
// EPI 0: +bias, relu -> bf16.   EPI 2: raw partial -> bf16 (split-K).
template <int EPI>
__global__ __launch_bounds__(512, 2)
void gemm256(const unsigned short* __restrict__ A, const unsigned short* __restrict__ Bt,
             const float* __restrict__ bias, unsigned short* __restrict__ C,
             int M, int N, int kstride, int ktiles, int splitk) {
  __shared__ unsigned short lA[2][2][128 * 64];   // [buf][row-half][row*64+swz(col)]
  __shared__ unsigned short lB[2][2][128 * 64];   // 128 KiB total

  const int tid  = threadIdx.x;
  const int lane = tid & 63;
  const int wave = tid >> 6;
  const int wr = wave >> 2;      // 0..1 : 128-row half
  const int wc = wave & 3;       // 0..3 : 64-col quarter

  // T1 XCD swizzle over the full grid (tiles*splitk, multiple of 8)
  const int nbx   = N >> 8;
  const int tiles = (M >> 8) * nbx;
  const int nwg   = tiles * splitk;
  int wg = blockIdx.x;
  wg = (wg & 7) * (nwg >> 3) + (wg >> 3);
  const int s    = wg / tiles;
  const int tt   = wg - s * tiles;
  const int brow = tt / nbx;
  const int bcol = tt % nbx;
  const int k0   = s * (ktiles * 64);

  // staging source offsets (pre-swizzled global col), dest is linear
  const unsigned short* Abase = A  + (size_t)(brow * 256) * kstride + k0;
  const unsigned short* Bbase = Bt + (size_t)(bcol * 256) * kstride + k0;
  int offA[2][2], offB[2][2];          // [half][j]
  #pragma unroll
  for (int h = 0; h < 2; ++h)
    #pragma unroll
    for (int j = 0; j < 2; ++j) {
      int f   = j * 512 + tid;
      int row = f >> 3;
      int cc  = ((f & 7) * 8) ^ ((row & 7) << 3);
      offA[h][j] = (h * 128 + row) * kstride + cc;
      offB[h][j] = offA[h][j];
    }

#define STAGE_A(buf, h, kt)  { stage16(Abase + offA[h][0] + (kt) * 64, &lA[buf][h][(size_t)tid * 8]); \
                               stage16(Abase + offA[h][1] + (kt) * 64, &lA[buf][h][(size_t)(512 + tid) * 8]); }
#define STAGE_B(buf, h, kt)  { stage16(Bbase + offB[h][0] + (kt) * 64, &lB[buf][h][(size_t)tid * 8]); \
                               stage16(Bbase + offB[h][1] + (kt) * 64, &lB[buf][h][(size_t)(512 + tid) * 8]); }

  // prologue: tile0 fully + tile1 A-half0  (10 wave-loads in flight)
  STAGE_A(0, 0, 0); STAGE_A(0, 1, 0); STAGE_B(0, 0, 0); STAGE_B(0, 1, 0);
  STAGE_A(1, 0, 1);
  asm volatile("s_waitcnt vmcnt(2)" ::: "memory");   // confirm tile0
  __builtin_amdgcn_s_barrier();

  f32x4 acc[8][4] = {};
  const int fr = lane & 15;
  const int fk = (lane >> 4) * 8;
  const int bh = wc >> 1;              // wave's B half
  const int br0 = (wc & 1) * 64;       // wave's row base inside B half

  bf16x8 af[4][2], bf0[2][2], bf1[2][2];

  for (int tau = 0; tau < ktiles; ++tau) {
    const int buf = tau & 1, nbuf = buf ^ 1;
    const bool st1 = (tau + 1 < ktiles);

    // ---- q0: stage A1[t+1]; read A m0-3 + B n0-1; MFMA m0-3 x n0-1 ----
    if (st1) STAGE_A(nbuf, 1, tau + 1);
    #pragma unroll
    for (int m = 0; m < 4; ++m)
      #pragma unroll
      for (int kk = 0; kk < 2; ++kk) {
        int row = m * 16 + fr;
        af[m][kk] = *(const bf16x8*)&lA[buf][wr][row * 64 + ((kk * 32 + fk) ^ ((row & 7) << 3))];
      }
    #pragma unroll
    for (int n = 0; n < 2; ++n)
      #pragma unroll
      for (int kk = 0; kk < 2; ++kk) {
        int row = br0 + n * 16 + fr;
        bf0[n][kk] = *(const bf16x8*)&lB[buf][bh][row * 64 + ((kk * 32 + fk) ^ ((row & 7) << 3))];
      }
    asm volatile("s_waitcnt lgkmcnt(8)" ::: "memory");
    __builtin_amdgcn_s_barrier();
    asm volatile("s_waitcnt lgkmcnt(0)" ::: "memory");
    __builtin_amdgcn_s_setprio(1);
    #pragma unroll
    for (int kk = 0; kk < 2; ++kk)
      #pragma unroll
      for (int m = 0; m < 4; ++m)
        #pragma unroll
        for (int n = 0; n < 2; ++n)
          acc[m][n] = __builtin_amdgcn_mfma_f32_16x16x32_bf16(af[m][kk], bf0[n][kk], acc[m][n], 0, 0, 0);
    __builtin_amdgcn_s_setprio(0);
    __builtin_amdgcn_s_barrier();

    // ---- q1: stage B0[t+1]; read B n2-3; MFMA m0-3 x n2-3 ----
    if (st1) STAGE_B(nbuf, 0, tau + 1);
    #pragma unroll
    for (int n = 0; n < 2; ++n)
      #pragma unroll
      for (int kk = 0; kk < 2; ++kk) {
        int row = br0 + (2 + n) * 16 + fr;
        bf1[n][kk] = *(const bf16x8*)&lB[buf][bh][row * 64 + ((kk * 32 + fk) ^ ((row & 7) << 3))];
      }
    __builtin_amdgcn_s_barrier();
    asm volatile("s_waitcnt lgkmcnt(0)" ::: "memory");
    __builtin_amdgcn_s_setprio(1);
    #pragma unroll
    for (int kk = 0; kk < 2; ++kk)
      #pragma unroll
      for (int m = 0; m < 4; ++m)
        #pragma unroll
        for (int n = 0; n < 2; ++n)
          acc[m][2 + n] = __builtin_amdgcn_mfma_f32_16x16x32_bf16(af[m][kk], bf1[n][kk], acc[m][2 + n], 0, 0, 0);
    __builtin_amdgcn_s_setprio(0);
    __builtin_amdgcn_s_barrier();

    // ---- q2: stage B1[t+1]; read A m4-7; MFMA m4-7 x n2-3 ----
    if (st1) STAGE_B(nbuf, 1, tau + 1);
    #pragma unroll
    for (int m = 0; m < 4; ++m)
      #pragma unroll
      for (int kk = 0; kk < 2; ++kk) {
        int row = (4 + m) * 16 + fr;
        af[m][kk] = *(const bf16x8*)&lA[buf][wr][row * 64 + ((kk * 32 + fk) ^ ((row & 7) << 3))];
      }
    __builtin_amdgcn_s_barrier();
    asm volatile("s_waitcnt lgkmcnt(0)" ::: "memory");
    __builtin_amdgcn_s_setprio(1);
    #pragma unroll
    for (int kk = 0; kk < 2; ++kk)
      #pragma unroll
      for (int m = 0; m < 4; ++m)
        #pragma unroll
        for (int n = 0; n < 2; ++n)
          acc[4 + m][2 + n] = __builtin_amdgcn_mfma_f32_16x16x32_bf16(af[m][kk], bf1[n][kk], acc[4 + m][2 + n], 0, 0, 0);
    __builtin_amdgcn_s_setprio(0);
    __builtin_amdgcn_s_barrier();

    // ---- q3: stage A0[t+2]; counted vmcnt; MFMA m4-7 x n0-1 ----
    if (tau + 2 < ktiles) {
      STAGE_A(buf, 0, tau + 2);
      asm volatile("s_waitcnt vmcnt(2)" ::: "memory");   // confirms all of tile t+1
    } else {
      asm volatile("s_waitcnt vmcnt(0)" ::: "memory");   // tail drain (last 2 tiles only)
    }
    __builtin_amdgcn_s_barrier();
    __builtin_amdgcn_s_setprio(1);
    #pragma unroll
    for (int kk = 0; kk < 2; ++kk)
      #pragma unroll
      for (int m = 0; m < 4; ++m)
        #pragma unroll
        for (int n = 0; n < 2; ++n)
          acc[4 + m][n] = __builtin_amdgcn_mfma_f32_16x16x32_bf16(af[m][kk], bf0[n][kk], acc[4 + m][n], 0, 0, 0);
    __builtin_amdgcn_s_setprio(0);
  }

  // ---- epilogue.  C/D: col = lane&15, row = (lane>>4)*4 + i ----
  unsigned short* Cs = C + (size_t)s * M * N;
  const int crow0 = brow * 256 + wr * 128 + (lane >> 4) * 4;
  const int ccol0 = bcol * 256 + wc * 64 + fr;
  #pragma unroll
  for (int n = 0; n < 4; ++n) {
    const int col = ccol0 + n * 16;
    const float bv = (EPI == 0) ? bias[col] : 0.f;
    #pragma unroll
    for (int m = 0; m < 8; ++m) {
      #pragma unroll
      for (int i = 0; i < 4; ++i) {
        const size_t idx = (size_t)(crow0 + m * 16 + i) * N + col;
        float v = acc[m][n][i];
        if (EPI == 0) { v += bv; v = v > 0.f ? v : 0.f; }
        Cs[idx] = f32_to_bf16(v);
      }
    }
  }
#undef STAGE_A
#undef STAGE_B
}

// ---------------- split-K reduce + bias + sigmoid ----------------
__global__ void reduce_sigmoid(const unsigned short* __restrict__ p,
                               const float* __restrict__ b2, float* __restrict__ out) {
  const size_t i = (size_t)blockIdx.x * blockDim.x + threadIdx.x;  // 8-elem chunk id
  const size_t base = i * 8;
  const int col = (int)(base & (OUT_F - 1));
  u16x8 a = *(const u16x8*)&p[base];
  u16x8 b = *(const u16x8*)&p[(size_t)BATCH * OUT_F + base];
  float4 o0, o1;
  float* o = (float*)&o0;
  #pragma unroll
  for (int j = 0; j < 8; ++j) {
    float z = bf16_to_f32(a[j]) + bf16_to_f32(b[j]) + b2[col + j];
    float r = 1.f / (1.f + __expf(-z));
    if (j < 4) ((float*)&o0)[j] = r; else ((float*)&o1)[j - 4] = r;
  }
  (void)o;
  *(float4*)&out[base] = o0;
  *(float4*)&out[base + 4] = o1;
}

// ---------------- launch ----------------

extern "C" void kernel_launch(void* const* d_in, const int* in_sizes, int n_in,
                              void* d_out, int out_size, void* d_ws, size_t ws_size,
                              hipStream_t stream) {
  const float* x  = (const float*)d_in[0];
  const float* W1 = (const float*)d_in[1];
  const float* b1 = (const float*)d_in[2];
  const float* W2 = (const float*)d_in[3];
  const float* b2 = (const float*)d_in[4];
  float* out = (float*)d_out;

  char* ws = (char*)d_ws;
  const size_t MB = 1024 * 1024;
  // [0,16)  x_bf   (dead after gemm1)     | reused as parts[0] (16MB)
  // [16,48) W1t    (dead after gemm1)     | [16,32) reused as parts[1]
  // [48,80) W2t
  // [80,144) h_bf
  unsigned short* x_bf  = (unsigned short*)(ws);
  unsigned short* W1t   = (unsigned short*)(ws + 16 * MB);
  unsigned short* W2t   = (unsigned short*)(ws + 48 * MB);
  unsigned short* h_bf  = (unsigned short*)(ws + 80 * MB);
  unsigned short* parts = (unsigned short*)(ws);            // [2][BATCH][OUT_F] bf16

  cvt_f32_bf16<<<4096, 256, 0, stream>>>(x, x_bf, (BATCH * IN_F) / 4);
  transpose2<<<8192, 256, 0, stream>>>(W1, W1t, W2, W2t);

  gemm256<0><<<(BATCH / 256) * (HID_F / 256), 512, 0, stream>>>(
      x_bf, W1t, b1, h_bf, BATCH, HID_F, IN_F, IN_F / 64, 1);

  gemm256<2><<<(BATCH / 256) * (OUT_F / 256) * 2, 512, 0, stream>>>(
      h_bf, W2t, nullptr, parts, BATCH, OUT_F, HID_F, (HID_F / 2) / 64, 2);

  reduce_sigmoid<<<(BATCH * OUT_F) / 8 / 256, 256, 0, stream>>>(parts, b2, out);
}